// Round 4
// baseline (577.367 us; speedup 1.0000x reference)
//
#include <hip/hip_runtime.h>

// SuperONN1d as implicit GEMM on bf16 MFMA (32x32x16).
// GEMM: M=Cout=128, N=B*L, K=9*3*128=3456 (k = tap*384 + q*128 + ci).
// R4: A-traffic-minimal wave shape. Each wave = 32co x 128l:
//   per K16 chunk: 1 A-frag (1KB, global/L2) amortized over 4 MFMAs (nB=4).
//   16 waves = 4 wm(co32) x 4 wk(K-quarter, split inside each tap -> affine).
//   Every A fragment is read exactly once per block (884 KB/block vs 3.5 MB in R3).
// B staged in LDS bf16, row stride 386 shorts (193 dwords, odd -> conflict-free).
// 4-way K-split reduced via sequential LDS tree reusing xq.

#define B_    16
#define CIN   128
#define L_    8192
#define COUT  128
#define K_    9
#define PAD_  4
#define QMAX  3

#define TN    128
#define XW    (TN + K_ - 1)       // 136 staged positions
#define KQ    (QMAX * CIN)        // 384 GEMM-K per tap
#define XROW  (KQ + 2)            // 386 shorts = 193 dwords (odd -> no bank conflicts)
#define KTOT  (K_ * KQ)           // 3456
#define NKT   (KTOT / 16)         // 216 K16 fragments per co32 row-group
#define RSTR  129                 // f32 reduction scratch l-stride (dwords)

typedef __attribute__((ext_vector_type(8)))  short bf16x8;   // one MFMA operand frag
typedef __attribute__((ext_vector_type(16))) float f32x16;   // 32x32 accumulator

__device__ __forceinline__ unsigned short f2bf(float v) {
    union { float f; unsigned u; } cv; cv.f = v;
    unsigned u = cv.u;
    return (unsigned short)((u + 0x7FFFu + ((u >> 16) & 1u)) >> 16);  // RNE
}

// ---- prep: w[co][qc][tap] (f32) -> A fragments (bf16) ----
// wb layout: [wm(4)][kt(216)][lane(64)][8]:
//   co = wm*32 + (lane&31), k = kt*16 + (lane>>5)*8 + i.
__global__ __launch_bounds__(256) void prep_weights(
    const float* __restrict__ w, unsigned short* __restrict__ wb)
{
    int idx = blockIdx.x * 256 + threadIdx.x;
    if (idx >= COUT * KTOT) return;
    const int wm   = idx / (NKT * 512);
    const int r    = idx - wm * (NKT * 512);
    const int kt   = r >> 9;
    const int r2   = r & 511;
    const int lane = r2 >> 3;
    const int i    = r2 & 7;
    const int co   = wm * 32 + (lane & 31);
    const int k    = kt * 16 + ((lane >> 5) << 3) + i;
    const int tap  = k / KQ;
    const int qc   = k - tap * KQ;
    wb[idx] = f2bf(w[((size_t)co * KQ + qc) * K_ + tap]);
}

__global__ __launch_bounds__(1024, 4) void superonn_mfma(
    const float*          __restrict__ x,       // [B, CIN, L]
    const unsigned short* __restrict__ wb,      // A frags, bf16
    const float*          __restrict__ bias,    // [COUT]
    const float*          __restrict__ shifts,  // [CIN, 2]
    float*                __restrict__ out)     // [B, COUT, L]
{
    __shared__ __align__(16) unsigned short xq[XW * XROW];  // 104,992 B

    const int l0  = blockIdx.x * TN;
    const int b   = blockIdx.y;
    const int tid = threadIdx.x;

    // ---- stage B: shift-lerp + powers, f32 math -> bf16 ----
    const float* xb = x + (size_t)b * CIN * L_;
    for (int it = 0; it < (CIN * XW) / 1024; ++it) {   // 17 exact
        const int idx = it * 1024 + tid;
        const int ci  = idx / XW;
        const int pp  = idx - ci * XW;
        const int p   = l0 + pp - PAD_;
        float xs = 0.0f;
        if (p >= 0 && p < L_) {                        // conv zero padding
            const float sh  = shifts[2 * ci] * 4.0f;   // MAX_SHIFT
            const float pos = (float)p + sh;
            const float fl  = floorf(pos);
            const int   i0  = (int)fl;
            const float w1  = pos - fl;
            const float v0  = (i0     >= 0 && i0     < L_) ? xb[ci * L_ + i0]     : 0.0f;
            const float v1  = (i0 + 1 >= 0 && i0 + 1 < L_) ? xb[ci * L_ + i0 + 1] : 0.0f;
            xs = fmaf(w1, v1 - v0, v0);
        }
        const float x2 = xs * xs;
        const float x3 = x2 * xs;
        unsigned short* row = &xq[pp * XROW];
        row[ci]           = f2bf(xs);
        row[CIN + ci]     = f2bf(x2);
        row[2 * CIN + ci] = f2bf(x3);
    }
    __syncthreads();

    // ---- wave decomposition: wm(co32) x wk(K-quarter); each wave does all 128 l ----
    const int lane = tid & 63;
    const int wv   = tid >> 6;
    const int wk   = wv & 3;           // K-quarter: kq-chunks {wk*6 .. wk*6+5} per tap
    const int wm   = wv >> 2;          // co32 group
    const int h    = lane >> 5;
    const int n5   = lane & 31;

    f32x16 acc[4];
#pragma unroll
    for (int jl = 0; jl < 4; ++jl) acc[jl] = (f32x16){};

    // A: frag (wm, kt = tap*24 + wk*6 + j); lane-contiguous 1KB frags
    const unsigned short* abase = wb + ((size_t)(wm * NKT + wk * 6) << 9) + lane * 8;
    // B: row = jl*32 + n5 + tap, col = wk*96 + j*16 + h*8
    const unsigned short* bbase = &xq[n5 * XROW + wk * 96 + h * 8];

    for (int tap = 0; tap < K_; ++tap) {
        const unsigned short* at = abase + (size_t)tap * (24 * 512);
        const unsigned short* bt = bbase + tap * XROW;
#pragma unroll
        for (int j = 0; j < 6; ++j) {
            const bf16x8 a = *(const bf16x8*)(at + j * 512);
#pragma unroll
            for (int jl = 0; jl < 4; ++jl) {
                const bf16x8 bq = *(const bf16x8*)(bt + jl * 32 * XROW + j * 16);
                acc[jl] = __builtin_amdgcn_mfma_f32_32x32x16_bf16(a, bq, acc[jl], 0, 0, 0);
            }
        }
    }

    // ---- 4-way K-split reduction via LDS tree (reuse xq), + bias, store ----
    __syncthreads();                    // all B reads done; xq reusable
    float* red = (float*)xq;            // [128co][RSTR] = 66,048 B

    if (wk == 3) {
#pragma unroll
        for (int jl = 0; jl < 4; ++jl)
#pragma unroll
            for (int r = 0; r < 16; ++r) {
                const int co = wm * 32 + (r & 3) + 8 * (r >> 2) + 4 * h;
                red[co * RSTR + jl * 32 + n5] = acc[jl][r];
            }
    }
    __syncthreads();
    if (wk == 2) {
#pragma unroll
        for (int jl = 0; jl < 4; ++jl)
#pragma unroll
            for (int r = 0; r < 16; ++r) {
                const int co = wm * 32 + (r & 3) + 8 * (r >> 2) + 4 * h;
                float v = acc[jl][r] + red[co * RSTR + jl * 32 + n5];
                red[co * RSTR + jl * 32 + n5] = v;     // same-thread RMW, safe
            }
    }
    __syncthreads();
    if (wk == 1) {
#pragma unroll
        for (int jl = 0; jl < 4; ++jl)
#pragma unroll
            for (int r = 0; r < 16; ++r) {
                const int co = wm * 32 + (r & 3) + 8 * (r >> 2) + 4 * h;
                float v = acc[jl][r] + red[co * RSTR + jl * 32 + n5];
                red[co * RSTR + jl * 32 + n5] = v;
            }
    }
    __syncthreads();
    if (wk == 0) {
#pragma unroll
        for (int jl = 0; jl < 4; ++jl)
#pragma unroll
            for (int r = 0; r < 16; ++r) {
                const int co = wm * 32 + (r & 3) + 8 * (r >> 2) + 4 * h;
                const float v = acc[jl][r] + red[co * RSTR + jl * 32 + n5] + bias[co];
                out[((size_t)b * COUT + co) * L_ + l0 + jl * 32 + n5] = v;
            }
    }
}

extern "C" void kernel_launch(void* const* d_in, const int* in_sizes, int n_in,
                              void* d_out, int out_size, void* d_ws, size_t ws_size,
                              hipStream_t stream) {
    const float* x      = (const float*)d_in[0];  // 16*128*8192
    const float* w      = (const float*)d_in[1];  // 128*384*9
    const float* bias   = (const float*)d_in[2];  // 128
    const float* shifts = (const float*)d_in[3];  // 128*2
    float* out = (float*)d_out;

    unsigned short* wb = (unsigned short*)d_ws;   // 128*3456*2 = 884,736 B

    const int nw = COUT * KTOT;                   // 442,368
    prep_weights<<<(nw + 255) / 256, 256, 0, stream>>>(w, wb);

    dim3 grid(L_ / TN, B_);                       // 64 x 16 = 1024 blocks
    superonn_mfma<<<grid, 1024, 0, stream>>>(x, wb, bias, shifts, out);
}

// Round 5
// 398.623 us; speedup vs baseline: 1.4484x; 1.4484x over previous
//
#include <hip/hip_runtime.h>

// SuperONN1d as implicit GEMM on bf16 MFMA (32x32x16).
// GEMM: M=Cout=128, N=B*L, K=9*3*128=3456 (k = tap*384 + q*128 + ci).
// R5: async-pipelined A delivery (m97/AITER pattern).
//   - B operand: xq[136][386] halo tile in LDS (covers ALL K), staged once.
//   - A operand: streamed global->LDS via __builtin_amdgcn_global_load_lds,
//     triple-buffered 16KB chunks (K=64), prefetch distance 2,
//     s_waitcnt vmcnt(1) + raw s_barrier per chunk (loads in flight across barrier).
//   - 16 waves = 4 wk(K-split) x 2 wm2(co64) x 2 wl2(l64); per chunk each wave:
//     2 A ds_read_b128 + 2 B ds_read_b128 -> 4 MFMAs (read:MFMA = 1).
//   - Epilogue: 4-way K-split reduced via two parallel LDS regions.

#define B_    16
#define CIN   128
#define L_    8192
#define COUT  128
#define K_    9
#define PAD_  4
#define QMAX  3

#define TN    128
#define XW    (TN + K_ - 1)       // 136
#define KQ    (QMAX * CIN)        // 384 GEMM-K per tap
#define XROW  (KQ + 2)            // 386 shorts = 193 dwords (odd -> conflict-free)
#define KTOT  (K_ * KQ)           // 3456
#define CHK   64                  // K per staged A-chunk
#define NCHK  (KTOT / CHK)        // 54
#define CHKS  (COUT * CHK)        // 8192 shorts = 16 KB per chunk
#define XQS   (XW * XROW)         // 52,496 shorts
#define RSTR  129                 // f32 reduction row stride

typedef __attribute__((ext_vector_type(8)))  short bf16x8;
typedef __attribute__((ext_vector_type(16))) float f32x16;

__device__ __forceinline__ unsigned short f2bf(float v) {
    union { float f; unsigned u; } cv; cv.f = v;
    unsigned u = cv.u;
    return (unsigned short)((u + 0x7FFFu + ((u >> 16) & 1u)) >> 16);  // RNE
}

// ---- prep: w[co][qc][tap] (f32) -> chunked A fragments (bf16) ----
// wb[c][seg][lane][8]: seg = g*4 + kt; co = g*32 + (lane&31);
// k = c*64 + kt*16 + (lane>>5)*8 + i.
__global__ __launch_bounds__(256) void prep_weights(
    const float* __restrict__ w, unsigned short* __restrict__ wb)
{
    int idx = blockIdx.x * 256 + threadIdx.x;
    if (idx >= COUT * KTOT) return;
    const int c    = idx >> 13;          // /8192
    const int r    = idx & 8191;
    const int seg  = r >> 9;
    const int lane = (r >> 3) & 63;
    const int i    = idx & 7;
    const int g    = seg >> 2;
    const int kt   = seg & 3;
    const int co   = g * 32 + (lane & 31);
    const int k    = c * CHK + kt * 16 + ((lane >> 5) << 3) + i;
    const int tap  = k / KQ;
    const int qc   = k - tap * KQ;
    wb[idx] = f2bf(w[((size_t)co * KQ + qc) * K_ + tap]);
}

__global__ __launch_bounds__(1024, 4) void superonn_mfma(
    const float*          __restrict__ x,       // [B, CIN, L]
    const unsigned short* __restrict__ wb,      // A chunks, bf16
    const float*          __restrict__ bias,    // [COUT]
    const float*          __restrict__ shifts,  // [CIN, 2]
    float*                __restrict__ out)     // [B, COUT, L]
{
    __shared__ __align__(16) unsigned short smem[XQS + 3 * CHKS];  // 154,144 B
    unsigned short* xq = smem;
    unsigned short* ab = smem + XQS;            // 3 x 16KB A buffers

    const int l0  = blockIdx.x * TN;
    const int b   = blockIdx.y;
    const int tid = threadIdx.x;
    const int lane = tid & 63;
    const int wv   = tid >> 6;          // 0..15

    // ---- issue A prefetch of chunks 0,1 (each wave stages its 1KB segment) ----
    const unsigned short* wsrc = wb + (size_t)wv * 512 + lane * 8;
    __builtin_amdgcn_global_load_lds(
        (const __attribute__((address_space(1))) void*)(wsrc),
        (__attribute__((address_space(3))) void*)(&ab[0 * CHKS + wv * 512]), 16, 0, 0);
    __builtin_amdgcn_global_load_lds(
        (const __attribute__((address_space(1))) void*)(wsrc + CHKS),
        (__attribute__((address_space(3))) void*)(&ab[1 * CHKS + wv * 512]), 16, 0, 0);

    // ---- stage B: shift-lerp + powers, f32 math -> bf16 ----
    const float* xb = x + (size_t)b * CIN * L_;
    for (int it = 0; it < (CIN * XW) / 1024; ++it) {   // 17 exact
        const int idx = it * 1024 + tid;
        const int ci  = idx / XW;
        const int pp  = idx - ci * XW;
        const int p   = l0 + pp - PAD_;
        float xs = 0.0f;
        if (p >= 0 && p < L_) {                        // conv zero padding
            const float sh  = shifts[2 * ci] * 4.0f;   // MAX_SHIFT
            const float pos = (float)p + sh;
            const float fl  = floorf(pos);
            const int   i0  = (int)fl;
            const float w1  = pos - fl;
            const float v0  = (i0     >= 0 && i0     < L_) ? xb[ci * L_ + i0]     : 0.0f;
            const float v1  = (i0 + 1 >= 0 && i0 + 1 < L_) ? xb[ci * L_ + i0 + 1] : 0.0f;
            xs = fmaf(w1, v1 - v0, v0);
        }
        const float x2 = xs * xs;
        const float x3 = x2 * xs;
        unsigned short* row = &xq[pp * XROW];
        row[ci]           = f2bf(xs);
        row[CIN + ci]     = f2bf(x2);
        row[2 * CIN + ci] = f2bf(x3);
    }
    __syncthreads();    // xq staged AND chunks 0,1 resident (full drain, once)

    // ---- wave decomposition ----
    const int wk  = wv & 3;            // kt within chunk (4-way K split)
    const int wl2 = (wv >> 2) & 1;     // l half (64)
    const int wm2 = wv >> 3;           // co half (64)
    const int h   = lane >> 5;
    const int n5  = lane & 31;

    f32x16 acc[2][2];
#pragma unroll
    for (int i = 0; i < 2; ++i)
#pragma unroll
        for (int j = 0; j < 2; ++j) acc[i][j] = (f32x16){};

    const int aoff0 = (wm2 * 8 + wk) * 512 + lane * 8;   // shorts, within a buffer
    const int aoff1 = aoff0 + 2048;                      // co-group +1
    const unsigned short* bb = &xq[(wl2 * 64 + n5) * XROW + wk * 16 + h * 8];

    // ---- pipelined K-loop: 54 chunks, distance-2 prefetch, vmcnt(1) ----
    for (int tap = 0; tap < K_; ++tap) {
        const unsigned short* brow = bb + tap * XROW;
#pragma unroll
        for (int sub = 0; sub < 6; ++sub) {
            const int c  = tap * 6 + sub;
            int cn = c + 2; if (cn >= NCHK) cn -= NCHK;  // wrapped: harmless re-stage
            const int bc = sub % 3;          // c%3 (6 ≡ 0 mod 3) — static in unroll
            const int bn = (sub + 2) % 3;
            __builtin_amdgcn_global_load_lds(
                (const __attribute__((address_space(1))) void*)(wsrc + (size_t)cn * CHKS),
                (__attribute__((address_space(3))) void*)(&ab[bn * CHKS + wv * 512]),
                16, 0, 0);
            const unsigned short* abuf = ab + bc * CHKS;
            const bf16x8 a0 = *(const bf16x8*)(abuf + aoff0);
            const bf16x8 a1 = *(const bf16x8*)(abuf + aoff1);
            const unsigned short* bp = brow + sub * 64;
            const bf16x8 b0 = *(const bf16x8*)(bp);
            const bf16x8 b1 = *(const bf16x8*)(bp + 32 * XROW);
            acc[0][0] = __builtin_amdgcn_mfma_f32_32x32x16_bf16(a0, b0, acc[0][0], 0, 0, 0);
            acc[0][1] = __builtin_amdgcn_mfma_f32_32x32x16_bf16(a0, b1, acc[0][1], 0, 0, 0);
            acc[1][0] = __builtin_amdgcn_mfma_f32_32x32x16_bf16(a1, b0, acc[1][0], 0, 0, 0);
            acc[1][1] = __builtin_amdgcn_mfma_f32_32x32x16_bf16(a1, b1, acc[1][1], 0, 0, 0);
            __builtin_amdgcn_s_waitcnt(0x0F71);   // vmcnt(1): chunk c+1 staged, c+2 in flight
            __builtin_amdgcn_s_barrier();
        }
    }
    __syncthreads();   // full drain: wrapped prefetches land before LDS reuse

    // ---- epilogue: parallel 4-way K-reduction in LDS, + bias, store ----
    float* redA = (float*)smem;                 // [128][RSTR]
    float* redB = redA + COUT * RSTR;           // second region (132,096 B total)
    const int co_b = wm2 * 64;
    const int l_b  = wl2 * 64;

    if (wk == 3 || wk == 1) {
        float* dst = (wk == 3) ? redA : redB;
#pragma unroll
        for (int i = 0; i < 2; ++i)
#pragma unroll
            for (int j = 0; j < 2; ++j)
#pragma unroll
                for (int r = 0; r < 16; ++r) {
                    const int co = co_b + i * 32 + (r & 3) + 8 * (r >> 2) + 4 * h;
                    dst[co * RSTR + l_b + j * 32 + n5] = acc[i][j][r];
                }
    }
    __syncthreads();
    if (wk == 2 || wk == 0) {
        float* dst = (wk == 2) ? redA : redB;
#pragma unroll
        for (int i = 0; i < 2; ++i)
#pragma unroll
            for (int j = 0; j < 2; ++j)
#pragma unroll
                for (int r = 0; r < 16; ++r) {
                    const int co = co_b + i * 32 + (r & 3) + 8 * (r >> 2) + 4 * h;
                    dst[co * RSTR + l_b + j * 32 + n5] += acc[i][j][r];
                }
    }
    __syncthreads();
    if (wk == 0) {
#pragma unroll
        for (int i = 0; i < 2; ++i)
#pragma unroll
            for (int j = 0; j < 2; ++j)
#pragma unroll
                for (int r = 0; r < 16; ++r) {
                    const int co = co_b + i * 32 + (r & 3) + 8 * (r >> 2) + 4 * h;
                    const int l  = l_b + j * 32 + n5;
                    const float v = redA[co * RSTR + l] + redB[co * RSTR + l] + bias[co];
                    out[((size_t)b * COUT + co) * L_ + l0 + l] = v;
                }
    }
}

extern "C" void kernel_launch(void* const* d_in, const int* in_sizes, int n_in,
                              void* d_out, int out_size, void* d_ws, size_t ws_size,
                              hipStream_t stream) {
    const float* x      = (const float*)d_in[0];  // 16*128*8192
    const float* w      = (const float*)d_in[1];  // 128*384*9
    const float* bias   = (const float*)d_in[2];  // 128
    const float* shifts = (const float*)d_in[3];  // 128*2
    float* out = (float*)d_out;

    unsigned short* wb = (unsigned short*)d_ws;   // 128*3456*2 = 884,736 B

    const int nw = COUT * KTOT;                   // 442,368
    prep_weights<<<(nw + 255) / 256, 256, 0, stream>>>(w, wb);

    dim3 grid(L_ / TN, B_);                       // 64 x 16 = 1024 blocks
    superonn_mfma<<<grid, 1024, 0, stream>>>(x, wb, bias, shifts, out);
}

// Round 6
// 321.992 us; speedup vs baseline: 1.7931x; 1.2380x over previous
//
#include <hip/hip_runtime.h>

// SuperONN1d = implicit GEMM, restructured to the m97 proven shape.
//   Stage 1 (xq_prep): materialize XQ_T[b][lp][qc] bf16 in d_ws, lp = l+4
//     (4 zero guard rows each side absorb conv padding), qc = q*128+ci.
//     XQ row = 384 shorts = 768 B, contiguous -> DMA-stageable k-major B rows.
//   Stage 2 (prep_weights): A[co][k] -> per-chunk swizzled fragments so an
//     identity DMA copy produces a XOR-swizzled LDS tile (conflict-free reads).
//   Stage 3 (gemm): 1024 blocks x 256 thr (4 waves), 128co x 128l tile,
//     BK=64, 32 KB LDS -> 4 blocks/CU resident (cross-block overlap hides
//     barrier drains — the thing R2..R5's 1-block/CU designs lacked).
//     Per chunk per wave: 8 DMA issues, sync, 16 ds_read_b128 + 16 MFMA, sync.

#define B_    16
#define CIN   128
#define L_    8192
#define COUT  128
#define K_    9
#define QMAX  3
#define KQ    (QMAX * CIN)        // 384
#define KTOT  (K_ * KQ)           // 3456
#define BK    64
#define NCHK  (KTOT / BK)         // 54
#define GUARD 4
#define LROWS (L_ + 2 * GUARD)    // 8200
#define XQOFF (1u << 20)          // XQ at d_ws + 1 MB (A fragments first)

typedef __attribute__((ext_vector_type(8)))  short bf16x8;
typedef __attribute__((ext_vector_type(16))) float f32x16;
typedef __attribute__((ext_vector_type(4)))  int   int4v;

__device__ __forceinline__ unsigned short f2bf(float v) {
    union { float f; unsigned u; } cv; cv.f = v;
    unsigned u = cv.u;
    return (unsigned short)((u + 0x7FFFu + ((u >> 16) & 1u)) >> 16);  // RNE
}

// ---- A prep: w[co][qc][tap] -> wa[c][co][slot s8][i], swizzled:
//   LDS 16B-slot (co, s8) must hold elements k = c*64 + (s8 ^ (co&7))*8 + i
__global__ __launch_bounds__(256) void prep_weights(
    const float* __restrict__ w, unsigned short* __restrict__ wa)
{
    int g = blockIdx.x * 256 + threadIdx.x;
    if (g >= COUT * KTOT) return;
    const int c   = g >> 13;             // chunk (8192 shorts each)
    const int r   = g & 8191;
    const int co  = r >> 6;              // row = 64 shorts = 128 B
    const int s8  = (r >> 3) & 7;
    const int i   = r & 7;
    const int kk  = ((s8 ^ (co & 7)) << 3) | i;
    const int k   = c * BK + kk;
    const int tap = k / KQ;
    const int qc  = k - tap * KQ;
    wa[g] = f2bf(w[((size_t)co * KQ + qc) * K_ + tap]);
}

// ---- XQ prep: shift-lerp + powers -> XQ_T[b][lp][qc] bf16, guards zeroed ----
__global__ __launch_bounds__(256) void xq_prep(
    const float* __restrict__ x, const float* __restrict__ shifts,
    unsigned short* __restrict__ xq)
{
    __shared__ unsigned short tile[64 * KQ];     // 48 KB
    const int l0 = blockIdx.x * 64;
    const int b  = blockIdx.y;
    const float* xb = x + (size_t)b * CIN * L_;

    for (int it = 0; it < 32; ++it) {
        const int idx = it * 256 + threadIdx.x;
        const int ll  = idx >> 7;                // 0..63
        const int ci  = idx & 127;
        const float sh  = shifts[2 * ci] * 4.0f; // MAX_SHIFT
        const float pos = (float)(l0 + ll) + sh;
        const float fl  = floorf(pos);
        const int   i0  = (int)fl;
        const float w1  = pos - fl;
        const float v0  = (i0     >= 0 && i0     < L_) ? xb[ci * L_ + i0]     : 0.0f;
        const float v1  = (i0 + 1 >= 0 && i0 + 1 < L_) ? xb[ci * L_ + i0 + 1] : 0.0f;
        const float xs  = fmaf(w1, v1 - v0, v0);
        const float x2  = xs * xs;
        const float x3  = x2 * xs;
        tile[ll * KQ + ci]       = f2bf(xs);
        tile[ll * KQ + 128 + ci] = f2bf(x2);
        tile[ll * KQ + 256 + ci] = f2bf(x3);
    }
    __syncthreads();

    // contiguous 48 KB copy out (rows lp = l0+4 .. +67)
    const int4v* src = (const int4v*)tile;
    int4v* dst = (int4v*)(xq + ((size_t)b * LROWS + l0 + GUARD) * KQ);
    for (int it = 0; it < 12; ++it)
        dst[it * 256 + threadIdx.x] = src[it * 256 + threadIdx.x];

    if (blockIdx.x == 0) {          // zero guard rows lp 0..3
        int4v* g0 = (int4v*)(xq + (size_t)b * LROWS * KQ);
        if (threadIdx.x < 192) g0[threadIdx.x] = (int4v){0, 0, 0, 0};
    }
    if (blockIdx.x == gridDim.x - 1) {  // zero guard rows lp 8196..8199
        int4v* g1 = (int4v*)(xq + ((size_t)b * LROWS + L_ + GUARD) * KQ);
        if (threadIdx.x < 192) g1[threadIdx.x] = (int4v){0, 0, 0, 0};
    }
}

// ---- GEMM: m97-style 2-barrier K-loop, 4 blocks/CU ----
__global__ __launch_bounds__(256, 4) void gemm(
    const unsigned short* __restrict__ wa,   // [NCHK][128][64] swizzled bf16
    const unsigned short* __restrict__ xq,   // [B_][LROWS][KQ] bf16
    const float*          __restrict__ bias,
    float*                __restrict__ out)
{
    __shared__ __align__(16) unsigned short ldsA[COUT * BK];  // 16 KB
    __shared__ __align__(16) unsigned short ldsB[128 * BK];   // 16 KB

    const int l0   = blockIdx.x * 128;
    const int b    = blockIdx.y;
    const int tid  = threadIdx.x;
    const int lane = tid & 63;
    const int w    = tid >> 6;               // 0..3
    const int cobase = (w >> 1) * 64;
    const int nbase  = (w & 1) * 64;
    const int n5 = lane & 31;
    const int h  = lane >> 5;

    // B DMA lane pattern: lane j -> row (j>>3), slot (j&7)^((j>>3)&7)
    const int bj_row = lane >> 3;
    const size_t bLaneOff = (size_t)bj_row * KQ + (size_t)(((lane & 7) ^ (bj_row & 7)) << 3);

    // loop-invariant fragment LDS byte addresses (XOR-swizzled, conflict-free)
    int aaddr[2][4], baddr[2][4];
#pragma unroll
    for (int fi = 0; fi < 2; ++fi)
#pragma unroll
        for (int kc = 0; kc < 4; ++kc) {
            const int ar = cobase + fi * 32 + n5;
            aaddr[fi][kc] = ar * 128 + ((((kc << 1) | h) ^ (ar & 7)) << 4);
            const int br = nbase + fi * 32 + n5;
            baddr[fi][kc] = br * 128 + ((((kc << 1) | h) ^ (br & 7)) << 4);
        }

    f32x16 acc[2][2];
#pragma unroll
    for (int i = 0; i < 2; ++i)
#pragma unroll
        for (int j = 0; j < 2; ++j) acc[i][j] = (f32x16){};

    const unsigned short* xqb = xq + (size_t)b * LROWS * KQ;

    for (int tap = 0; tap < K_; ++tap) {
        const unsigned short* brow = xqb + (size_t)(l0 + tap) * KQ + bLaneOff;
#pragma unroll 1
        for (int s = 0; s < 6; ++s) {
            const int c = tap * 6 + s;
            const unsigned short* agsrc = wa + (size_t)c * 8192 + (size_t)(w * 4) * 512 + lane * 8;
            const unsigned short* bgsrc = brow + (size_t)(w * 4) * 8 * KQ + s * 64;
#pragma unroll
            for (int i = 0; i < 4; ++i) {
                __builtin_amdgcn_global_load_lds(
                    (const __attribute__((address_space(1))) void*)(agsrc + i * 512),
                    (__attribute__((address_space(3))) void*)((char*)ldsA + (w * 4 + i) * 1024),
                    16, 0, 0);
                __builtin_amdgcn_global_load_lds(
                    (const __attribute__((address_space(1))) void*)(bgsrc + (size_t)i * 8 * KQ),
                    (__attribute__((address_space(3))) void*)((char*)ldsB + (w * 4 + i) * 1024),
                    16, 0, 0);
            }
            __syncthreads();   // drains vmcnt(0): tiles resident
#pragma unroll
            for (int kc = 0; kc < 4; ++kc) {
                const bf16x8 a0 = *(const bf16x8*)((const char*)ldsA + aaddr[0][kc]);
                const bf16x8 a1 = *(const bf16x8*)((const char*)ldsA + aaddr[1][kc]);
                const bf16x8 b0 = *(const bf16x8*)((const char*)ldsB + baddr[0][kc]);
                const bf16x8 b1 = *(const bf16x8*)((const char*)ldsB + baddr[1][kc]);
                acc[0][0] = __builtin_amdgcn_mfma_f32_32x32x16_bf16(a0, b0, acc[0][0], 0, 0, 0);
                acc[0][1] = __builtin_amdgcn_mfma_f32_32x32x16_bf16(a0, b1, acc[0][1], 0, 0, 0);
                acc[1][0] = __builtin_amdgcn_mfma_f32_32x32x16_bf16(a1, b0, acc[1][0], 0, 0, 0);
                acc[1][1] = __builtin_amdgcn_mfma_f32_32x32x16_bf16(a1, b1, acc[1][1], 0, 0, 0);
            }
            __syncthreads();   // all reads done before next chunk's DMA overwrites
        }
    }

    // ---- epilogue: + bias, coalesced stores ----
#pragma unroll
    for (int fi = 0; fi < 2; ++fi)
#pragma unroll
        for (int bj = 0; bj < 2; ++bj)
#pragma unroll
            for (int r = 0; r < 16; ++r) {
                const int co = cobase + fi * 32 + (r & 3) + 8 * (r >> 2) + 4 * h;
                const int l  = l0 + nbase + bj * 32 + n5;
                out[((size_t)(b * COUT + co)) * L_ + l] = acc[fi][bj][r] + bias[co];
            }
}

extern "C" void kernel_launch(void* const* d_in, const int* in_sizes, int n_in,
                              void* d_out, int out_size, void* d_ws, size_t ws_size,
                              hipStream_t stream) {
    const float* x      = (const float*)d_in[0];  // 16*128*8192
    const float* w      = (const float*)d_in[1];  // 128*384*9
    const float* bias   = (const float*)d_in[2];  // 128
    const float* shifts = (const float*)d_in[3];  // 128*2
    float* out = (float*)d_out;

    const size_t need = (size_t)XQOFF + (size_t)B_ * LROWS * KQ * 2;  // ~101.8 MB
    if (ws_size < need) return;   // clean fail instead of OOB corruption

    unsigned short* wa = (unsigned short*)d_ws;                       // 884,736 B
    unsigned short* xq = (unsigned short*)((char*)d_ws + XQOFF);      // 100.76 MB

    const int nw = COUT * KTOT;                                       // 442,368
    prep_weights<<<(nw + 255) / 256, 256, 0, stream>>>(w, wa);

    dim3 gq(L_ / 64, B_);                                             // 128 x 16
    xq_prep<<<gq, 256, 0, stream>>>(x, shifts, xq);

    dim3 gg(L_ / 128, B_);                                            // 64 x 16 = 1024
    gemm<<<gg, 256, 0, stream>>>(wa, xq, bias, out);
}